// Round 2
// baseline (1707.233 us; speedup 1.0000x reference)
//
#include <hip/hip_runtime.h>
#include <stdint.h>

// ============================================================================
// Windowed attention (SAM-style), MI355X gfx950.
// B=256, N=196 (14x14), C=768, 12 heads x 64.
// R2: GEMMs = 256x256-tile 8-wave double-buffered 8-phase (unchanged).
// R3: attn rewritten swapped-operand (S^T = mfma(K,Q)):
//     - qrow lands on lane&15 -> row-sum = 2 shfl_xor, inv is lane-local
//     - P never touches LDS: PV B-frag (P^T) built via 8 shfl + 4 sel per
//       32-key step (replaces 52 conflicted ds_write_b16 + Ps reads)
//     - rel bias as T^T in per-wave [28][16] f32 LDS (conflict-free reads)
//     - LDS 53248 -> 40960 (4 blocks/CU), launch_bounds(256,3) caps VGPR 168
// ============================================================================

typedef __attribute__((ext_vector_type(8))) short bf16x8;   // 8 bf16 = 4 VGPRs
typedef __attribute__((ext_vector_type(4))) float f32x4;
typedef __attribute__((ext_vector_type(4))) unsigned int u32x4;
typedef unsigned short u16;
typedef unsigned int u32;

__device__ __forceinline__ u16 f2bf(float f) {
  u32 x = __float_as_uint(f);
  x += 0x7fffu + ((x >> 16) & 1u);   // round-to-nearest-even
  return (u16)(x >> 16);
}

__device__ __forceinline__ u32 pack2bf(float a, float b) {
  return (u32)f2bf(a) | ((u32)f2bf(b) << 16);
}

__device__ __forceinline__ void gload_lds16(const void* g, void* l) {
  __builtin_amdgcn_global_load_lds(
      (__attribute__((address_space(1))) void*)g,
      (__attribute__((address_space(3))) void*)l, 16, 0, 0);
}

// ---------------------------------------------------------------------------
__global__ __launch_bounds__(256) void cvt_bf16(const float* __restrict__ src,
                                                u16* __restrict__ dst, int n4) {
  int i = blockIdx.x * 256 + threadIdx.x;
  if (i < n4) {
    float4 f = ((const float4*)src)[i];
    uint2 p;
    p.x = pack2bf(f.x, f.y);
    p.y = pack2bf(f.z, f.w);
    ((uint2*)dst)[i] = p;
  }
}

// ---------------------------------------------------------------------------
// 256x256-tile bf16 GEMM, BK=64, K=768 (12 K-tiles), B^T weights.
// (unchanged from R2)
__device__ __forceinline__ void stage8(const u16* pA, const u16* pB,
                                       char* dstA, int k0) {
#pragma unroll
  for (int i = 0; i < 4; i++)
    gload_lds16(pA + (size_t)i * 49152 + k0, dstA + i * 8192);
#pragma unroll
  for (int i = 0; i < 4; i++)
    gload_lds16(pB + (size_t)i * 49152 + k0, dstA + 32768 + i * 8192);
}

template <int MODE, int NT>
__global__ __launch_bounds__(512, 2) void gemm256(
    const u16* __restrict__ A, const u16* __restrict__ W,
    const float* __restrict__ bias, u16* __restrict__ qb, u16* __restrict__ kb,
    u16* __restrict__ vb, float* __restrict__ outf) {
  __shared__ char lds[131072];   // 2 x (32KB A + 32KB B)

  const int t = threadIdx.x;
  const int lane = t & 63, wv = t >> 6;
  const int quad = lane >> 4, l15 = lane & 15;
  const int wm = wv >> 2, wn = wv & 3;   // 2 x 4 wave grid

  // ---- bijective XCD-chunked block swizzle (m204), n-tile fastest ----
  const u32 nwg = gridDim.x;
  const u32 wg = blockIdx.x;
  const u32 qd = nwg >> 3, rm = nwg & 7;
  const u32 xcd = wg & 7, loc = wg >> 3;
  const u32 swz = (xcd < rm) ? (xcd * (qd + 1) + loc)
                             : (rm * (qd + 1) + (xcd - rm) * qd + loc);
  const int mtile = swz / NT;
  const int ntile = (int)swz - mtile * NT;
  const int m0 = mtile << 8, n0 = ntile << 8;

  // ---- staging addresses (thread-constant swizzle) ----
  const int srow = t >> 3;
  const int scol = ((t & 7) ^ (srow & 7)) << 3;   // elements
  const u16* pA = A + (size_t)(m0 + srow) * 768 + scol;
  const u16* pB = W + (size_t)(n0 + srow) * 768 + scol;
  char* sdst = lds + t * 16;

  // ---- ds_read byte offsets (within current buffer) ----
  const int swz0 = ((quad) ^ (l15 & 7)) << 4;        // k-step 0
  const int swz1 = ((4 + quad) ^ (l15 & 7)) << 4;    // k-step 1
  const int arow = (wm * 128 + l15) * 128;
  const int brow = 32768 + (wn * 64 + l15) * 128;

  f32x4 acc[8][4];
#pragma unroll
  for (int i = 0; i < 8; i++)
#pragma unroll
    for (int j = 0; j < 4; j++) acc[i][j] = (f32x4){0.f, 0.f, 0.f, 0.f};

  // ---- prologue: stage tile 0 ----
  stage8(pA, pB, sdst, 0);
  asm volatile("s_waitcnt vmcnt(0)" ::: "memory");
  __builtin_amdgcn_s_barrier();

  bf16x8 af[4][2], bfr[4][2];
  for (int kt = 0; kt < 12; ++kt) {
    char* bufc = lds + ((kt & 1) << 16);
    char* nsdst = sdst + (((kt & 1) ^ 1) << 16);
    const int k0n = (kt + 1) << 6;

    // ======== P0: A rows 0-63 + B cols 0-31; stage next tile ========
#pragma unroll
    for (int mf = 0; mf < 4; mf++) {
      af[mf][0] = *(const bf16x8*)(bufc + arow + mf * 2048 + swz0);
      af[mf][1] = *(const bf16x8*)(bufc + arow + mf * 2048 + swz1);
    }
#pragma unroll
    for (int nf = 0; nf < 2; nf++) {
      bfr[nf][0] = *(const bf16x8*)(bufc + brow + nf * 2048 + swz0);
      bfr[nf][1] = *(const bf16x8*)(bufc + brow + nf * 2048 + swz1);
    }
    if (kt < 11) stage8(pA, pB, nsdst, k0n);
    __builtin_amdgcn_s_barrier();
    asm volatile("s_waitcnt lgkmcnt(0)" ::: "memory");
    __builtin_amdgcn_s_setprio(1);
#pragma unroll
    for (int k = 0; k < 2; k++)
#pragma unroll
      for (int mf = 0; mf < 4; mf++)
#pragma unroll
        for (int nf = 0; nf < 2; nf++)
          acc[mf][nf] = __builtin_amdgcn_mfma_f32_16x16x32_bf16(
              af[mf][k], bfr[nf][k], acc[mf][nf], 0, 0, 0);
    __builtin_amdgcn_s_setprio(0);
    __builtin_amdgcn_s_barrier();

    // ======== P1: B cols 32-63 ========
#pragma unroll
    for (int nf = 2; nf < 4; nf++) {
      bfr[nf][0] = *(const bf16x8*)(bufc + brow + nf * 2048 + swz0);
      bfr[nf][1] = *(const bf16x8*)(bufc + brow + nf * 2048 + swz1);
    }
    __builtin_amdgcn_s_barrier();
    asm volatile("s_waitcnt lgkmcnt(0)" ::: "memory");
    __builtin_amdgcn_s_setprio(1);
#pragma unroll
    for (int k = 0; k < 2; k++)
#pragma unroll
      for (int mf = 0; mf < 4; mf++)
#pragma unroll
        for (int nf = 2; nf < 4; nf++)
          acc[mf][nf] = __builtin_amdgcn_mfma_f32_16x16x32_bf16(
              af[mf][k], bfr[nf][k], acc[mf][nf], 0, 0, 0);
    __builtin_amdgcn_s_setprio(0);
    __builtin_amdgcn_s_barrier();

    // ======== P2: A rows 64-127 ========
#pragma unroll
    for (int mf = 0; mf < 4; mf++) {
      af[mf][0] = *(const bf16x8*)(bufc + arow + (mf + 4) * 2048 + swz0);
      af[mf][1] = *(const bf16x8*)(bufc + arow + (mf + 4) * 2048 + swz1);
    }
    __builtin_amdgcn_s_barrier();
    asm volatile("s_waitcnt lgkmcnt(0)" ::: "memory");
    __builtin_amdgcn_s_setprio(1);
#pragma unroll
    for (int k = 0; k < 2; k++)
#pragma unroll
      for (int mf = 0; mf < 4; mf++)
#pragma unroll
        for (int nf = 0; nf < 2; nf++)
          acc[mf + 4][nf] = __builtin_amdgcn_mfma_f32_16x16x32_bf16(
              af[mf][k], bfr[nf][k], acc[mf + 4][nf], 0, 0, 0);
    __builtin_amdgcn_s_setprio(0);
    __builtin_amdgcn_s_barrier();

    // ======== P3: no ds_reads; drain next-tile staging at the end ========
    __builtin_amdgcn_s_setprio(1);
#pragma unroll
    for (int k = 0; k < 2; k++)
#pragma unroll
      for (int mf = 0; mf < 4; mf++)
#pragma unroll
        for (int nf = 2; nf < 4; nf++)
          acc[mf + 4][nf] = __builtin_amdgcn_mfma_f32_16x16x32_bf16(
              af[mf][k], bfr[nf][k], acc[mf + 4][nf], 0, 0, 0);
    __builtin_amdgcn_s_setprio(0);
    asm volatile("s_waitcnt vmcnt(0)" ::: "memory");
    __builtin_amdgcn_s_barrier();
  }

  // ---- epilogue ----
  if (MODE == 0) {
    const int which = n0 / 768;   // block-uniform (256 | 768-boundaries)
    u16* dst = (which == 0) ? qb : ((which == 1) ? kb : vb);
    const float sc = (which == 0) ? 0.125f : 1.0f;
    float bs[4];
    size_t hb[4];
#pragma unroll
    for (int nf = 0; nf < 4; nf++) {
      int n = n0 + wn * 64 + nf * 16 + l15;
      int cc = n - which * 768;
      bs[nf] = bias[n];
      hb[nf] = (size_t)(cc >> 6) * 12544 + (size_t)(cc & 63);
    }
#pragma unroll
    for (int mf = 0; mf < 8; mf++) {
#pragma unroll
      for (int r = 0; r < 4; r++) {
        int m = m0 + wm * 128 + mf * 16 + (quad << 2) + r;
        int bb = m / 196;
        int tok = m - bb * 196;
        size_t rb = (size_t)bb * 150528 + (size_t)tok * 64;
#pragma unroll
        for (int nf = 0; nf < 4; nf++)
          dst[rb + hb[nf]] = f2bf((acc[mf][nf][r] + bs[nf]) * sc);
      }
    }
  } else {
    float bs[4];
#pragma unroll
    for (int nf = 0; nf < 4; nf++)
      bs[nf] = bias[n0 + wn * 64 + nf * 16 + l15];
#pragma unroll
    for (int mf = 0; mf < 8; mf++) {
#pragma unroll
      for (int r = 0; r < 4; r++) {
        int m = m0 + wm * 128 + mf * 16 + (quad << 2) + r;
#pragma unroll
        for (int nf = 0; nf < 4; nf++)
          outf[(size_t)m * 768 + (n0 + wn * 64 + nf * 16 + l15)] =
              acc[mf][nf][r] + bs[nf];
      }
    }
  }
}

// ---------------------------------------------------------------------------
// Fused attention, swapped-operand form. One block per (b,h), 4 waves,
// wave-independent q-tiles (one barrier total, after V^T staging).
//
// S^T = mfma(K_frag, Q_frag): lane&15 = qrow, (quad,reg) = key.
//   -> row-sum = 2 shfl_xor(16,32); 1/sum lane-local at output.
// T^T = mfma(Rel_frag, Q_frag) -> per-wave LDS [28][16] f32, reads are
//   row-per-quad / col-per-lane (conflict-free within a 16-lane group).
// PV:  O^T = mfma(V^T_frag, P^T_frag); V^T from chunked Vt (contiguous
//   b128 reads); P^T built in-register: dest word w of quad q equals
//   pw2[2s+(q>>1)][w&1] shfl'd from lane l15+32(q&1)+16(w>>1).
// LDS = 26624 (Vt) + 14336 (TL) = 40960 -> 4 blocks/CU.
__global__ __launch_bounds__(256, 3) void attn_fused(
    const u16* __restrict__ qbuf, const u16* __restrict__ kbuf,
    const u16* __restrict__ vbuf, const float* __restrict__ rel_h,
    const float* __restrict__ rel_w, u16* __restrict__ aout) {
  __shared__ u16 Vt[26 * 512];        // 26 chunks x [64 d][8 keys] = 26624 B
  __shared__ float TL[4][2][28][16];  // per-wave T^T (h,w): 14336 B

  const int t = threadIdx.x;
  const int bh = blockIdx.x;
  const int b = bh / 12, h = bh - b * 12;
  const int lane = t & 63, wv = t >> 6;
  const int quad = lane >> 4, l15 = lane & 15;
  const size_t base = (size_t)bh * (196 * 64);

  // ---- stage V^T (chunked) ----
  for (int c = t; c < 196 * 8; c += 256) {
    int row = c >> 3, seg = c & 7;    // key row, d-segment
    uint4 vv = *(const uint4*)(vbuf + base + row * 64 + seg * 8);
    const u16* pv8 = (const u16*)&vv;
    u16* dst = Vt + (row >> 3) * 512 + (row & 7);
#pragma unroll
    for (int e = 0; e < 8; e++) dst[(seg * 8 + e) * 8] = pv8[e];
  }
  // zero keys 196..207 (chunks 24,25 tails) so PV never multiplies NaN bits
  for (int i = t; i < 12 * 64; i += 256) {
    int k = 196 + (i >> 6), d = i & 63;
    Vt[(k >> 3) * 512 + d * 8 + (k & 7)] = 0;
  }

  // ---- rel-pos frags (8): [half h/w][ntile][ks]; used as MFMA A-operand:
  //      lane holds Rel[nt*16+l15][ks*32 + quad*8 + j] ----
  bf16x8 brl[2][2][2];
#pragma unroll
  for (int half = 0; half < 2; half++) {
    const float* relp = half ? rel_w : rel_h;
#pragma unroll
    for (int nt = 0; nt < 2; nt++) {
      int ridx = nt * 16 + l15;
      if (ridx > 26) ridx = 26;       // dup; rows >=27 never stored
#pragma unroll
      for (int ks = 0; ks < 2; ks++) {
        const float* p = relp + ridx * 64 + ks * 32 + quad * 8;
        float4 f0 = *(const float4*)p;
        float4 f1 = *(const float4*)(p + 4);
        bf16x8 r;
        r[0] = (short)f2bf(f0.x); r[1] = (short)f2bf(f0.y);
        r[2] = (short)f2bf(f0.z); r[3] = (short)f2bf(f0.w);
        r[4] = (short)f2bf(f1.x); r[5] = (short)f2bf(f1.y);
        r[6] = (short)f2bf(f1.z); r[7] = (short)f2bf(f1.w);
        brl[half][nt][ks] = r;
      }
    }
  }
  __syncthreads();   // Vt ready (only barrier)

  float (*TLh)[16] = TL[wv][0];
  float (*TLw)[16] = TL[wv][1];
  const u16* kB = kbuf + base;
  const u16* qB = qbuf + base;

  // ---- wave-independent q-tiles ----
  for (int qt = wv; qt < 13; qt += 4) {
    // Q frags: lane holds Q[qt*16 + l15][quad*8 + j] (row-clamped)
    int qrl = qt * 16 + l15;
    if (qrl > 195) qrl = 195;
    bf16x8 aq0 = *(const bf16x8*)(qB + qrl * 64 + quad * 8);
    bf16x8 aq1 = *(const bf16x8*)(qB + qrl * 64 + 32 + quad * 8);
    const int hq = qrl / 14, wq = qrl - hq * 14;  // lane-local qrow coords

    // T^T = mfma(rel, q): out col=l15=qrow, row=r27
#pragma unroll
    for (int half = 0; half < 2; half++) {
#pragma unroll
      for (int nt = 0; nt < 2; nt++) {
        f32x4 tc = (f32x4){0.f, 0.f, 0.f, 0.f};
        tc = __builtin_amdgcn_mfma_f32_16x16x32_bf16(brl[half][nt][0], aq0, tc, 0, 0, 0);
        tc = __builtin_amdgcn_mfma_f32_16x16x32_bf16(brl[half][nt][1], aq1, tc, 0, 0, 0);
#pragma unroll
        for (int r = 0; r < 4; r++) {
          int r27 = nt * 16 + quad * 4 + r;
          if (r27 < 27) TL[wv][half][r27][l15] = tc[r];
        }
      }
    }

    // pass 1: S^T tiles + bias + exp; P kept in regs as bf16 pairs.
    // pw2[kt][w] = pack(P[key=kt*16+quad*4+2w], P[key+1]) for this lane's qrow.
    u32 pw2[13][2];
    float sm = 0.f;
#pragma unroll
    for (int kt = 0; kt < 13; kt++) {
      int keyl = kt * 16 + l15;
      int keyc = (keyl > 195) ? 195 : keyl;
      bf16x8 bk0 = *(const bf16x8*)(kB + keyc * 64 + quad * 8);
      bf16x8 bk1 = *(const bf16x8*)(kB + keyc * 64 + 32 + quad * 8);
      f32x4 s = (f32x4){0.f, 0.f, 0.f, 0.f};
      s = __builtin_amdgcn_mfma_f32_16x16x32_bf16(bk0, aq0, s, 0, 0, 0);
      s = __builtin_amdgcn_mfma_f32_16x16x32_bf16(bk1, aq1, s, 0, 0, 0);
      const int key0 = kt * 16 + quad * 4;
      const int hk0 = key0 / 14, wk0 = key0 - 14 * hk0;
      const bool valid = (kt < 12) || (quad == 0);
      float pr[4];
#pragma unroll
      for (int r = 0; r < 4; r++) {
        int cr = (wk0 + r >= 14) ? 1 : 0;
        int hk = hk0 + cr, wk = wk0 + r - 14 * cr;
        float v = s[r] + TLh[hq - hk + 13][l15] + TLw[wq - wk + 13][l15];
        float p = valid ? __expf(v) : 0.f;
        pr[r] = p;
        sm += p;
      }
      pw2[kt][0] = pack2bf(pr[0], pr[1]);
      pw2[kt][1] = pack2bf(pr[2], pr[3]);
    }
    sm += __shfl_xor(sm, 16, 64);
    sm += __shfl_xor(sm, 32, 64);
    const float inv = 1.0f / sm;

    // PV: O^T = mfma(V^T, P^T). 7 steps of 32 keys; step 6 half-masked.
    f32x4 oacc[4];
#pragma unroll
    for (int dt = 0; dt < 4; dt++) oacc[dt] = (f32x4){0.f, 0.f, 0.f, 0.f};
    const int srcA = l15 + ((quad & 1) << 5);
    const bool hi = (quad >> 1) != 0;
#pragma unroll
    for (int st = 0; st < 7; st++) {
      u32 w0, w1, w2, w3;
      if (st < 6) {
        u32 a0 = __shfl(pw2[2 * st][0], srcA), b0 = __shfl(pw2[2 * st + 1][0], srcA);
        u32 a1 = __shfl(pw2[2 * st][1], srcA), b1 = __shfl(pw2[2 * st + 1][1], srcA);
        u32 a2 = __shfl(pw2[2 * st][0], srcA + 16), b2 = __shfl(pw2[2 * st + 1][0], srcA + 16);
        u32 a3 = __shfl(pw2[2 * st][1], srcA + 16), b3 = __shfl(pw2[2 * st + 1][1], srcA + 16);
        w0 = hi ? b0 : a0; w1 = hi ? b1 : a1;
        w2 = hi ? b2 : a2; w3 = hi ? b3 : a3;
      } else {
        u32 a0 = __shfl(pw2[12][0], srcA);
        u32 a1 = __shfl(pw2[12][1], srcA);
        u32 a2 = __shfl(pw2[12][0], srcA + 16);
        u32 a3 = __shfl(pw2[12][1], srcA + 16);
        w0 = hi ? 0u : a0; w1 = hi ? 0u : a1;
        w2 = hi ? 0u : a2; w3 = hi ? 0u : a3;
      }
      u32x4 pbw = (u32x4){w0, w1, w2, w3};
      bf16x8 pb = __builtin_bit_cast(bf16x8, pbw);
      const bool mvalid = (st < 6) || (quad < 2);
#pragma unroll
      for (int dt = 0; dt < 4; dt++) {
        bf16x8 av = (bf16x8){0, 0, 0, 0, 0, 0, 0, 0};
        if (mvalid)
          av = *(const bf16x8*)(Vt + (st * 4 + quad) * 512 + (dt * 16 + l15) * 8);
        oacc[dt] = __builtin_amdgcn_mfma_f32_16x16x32_bf16(av, pb, oacc[dt], 0, 0, 0);
      }
    }

    // normalize + store: lane covers d = dt*16 + quad*4 + {0..3} at its qrow
    const int qrow = qt * 16 + l15;
    if (qrow < 196) {
      u16* op = aout + ((size_t)(b * 196 + qrow) * 12 + h) * 64;
#pragma unroll
      for (int dt = 0; dt < 4; dt++) {
        uint2 stv;
        stv.x = pack2bf(oacc[dt][0] * inv, oacc[dt][1] * inv);
        stv.y = pack2bf(oacc[dt][2] * inv, oacc[dt][3] * inv);
        *(uint2*)(op + dt * 16 + quad * 4) = stv;
      }
    }
  }
}

// ---------------------------------------------------------------------------
extern "C" void kernel_launch(void* const* d_in, const int* in_sizes, int n_in,
                              void* d_out, int out_size, void* d_ws, size_t ws_size,
                              hipStream_t stream) {
  (void)in_sizes; (void)n_in; (void)out_size; (void)ws_size;
  const float* x      = (const float*)d_in[0];
  const float* qkv_w  = (const float*)d_in[1];
  const float* qkv_b  = (const float*)d_in[2];
  const float* rel_h  = (const float*)d_in[3];
  const float* rel_w  = (const float*)d_in[4];
  const float* proj_w = (const float*)d_in[5];
  const float* proj_b = (const float*)d_in[6];
  float* out = (float*)d_out;

  char* ws = (char*)d_ws;
  u16* xbf  = (u16*)(ws);              // aliased: x_bf16, then attn_out
  u16* qbuf = (u16*)(ws + 77070336);
  u16* kbuf = (u16*)(ws + 154140672);
  u16* vbuf = (u16*)(ws + 231211008);
  u16* wqb  = (u16*)(ws + 308281344);
  u16* wpb  = (u16*)(ws + 311820288);

  cvt_bf16<<<37632, 256, 0, stream>>>(x, xbf, 38535168 / 4);
  cvt_bf16<<<1728, 256, 0, stream>>>(qkv_w, wqb, 1769472 / 4);
  cvt_bf16<<<576, 256, 0, stream>>>(proj_w, wpb, 589824 / 4);

  // QKV: M=50176 (196 tiles), N=2304 (9 tiles), K=768
  gemm256<0, 9><<<1764, 512, 0, stream>>>(xbf, wqb, qkv_b, qbuf, kbuf, vbuf,
                                          nullptr);
  attn_fused<<<3072, 256, 0, stream>>>(qbuf, kbuf, vbuf, rel_h, rel_w, xbf);
  // proj: N=768 (3 tiles)
  gemm256<1, 3><<<588, 512, 0, stream>>>(xbf, wpb, proj_b, nullptr, nullptr,
                                         nullptr, out);
}

// Round 3
// 991.333 us; speedup vs baseline: 1.7222x; 1.7222x over previous
//
#include <hip/hip_runtime.h>
#include <stdint.h>

// ============================================================================
// Windowed attention (SAM-style), MI355X gfx950.
// B=256, N=196 (14x14), C=768, 12 heads x 64.
// R2: GEMMs = 256x256-tile 8-wave double-buffered 8-phase (unchanged).
// R4: attn = R3 swapped-operand structure, but launch_bounds(256) ONLY.
//     R3's (256,3) made the allocator target ~84 VGPR -> spilled pw2/brl to
//     scratch -> 3 GB HBM scratch traffic (FETCH 1.88GB, WRITE 1.19GB),
//     1146us. No other change: clean A/B on the register cap.
// ============================================================================

typedef __attribute__((ext_vector_type(8))) short bf16x8;   // 8 bf16 = 4 VGPRs
typedef __attribute__((ext_vector_type(4))) float f32x4;
typedef __attribute__((ext_vector_type(4))) unsigned int u32x4;
typedef unsigned short u16;
typedef unsigned int u32;

__device__ __forceinline__ u16 f2bf(float f) {
  u32 x = __float_as_uint(f);
  x += 0x7fffu + ((x >> 16) & 1u);   // round-to-nearest-even
  return (u16)(x >> 16);
}

__device__ __forceinline__ u32 pack2bf(float a, float b) {
  return (u32)f2bf(a) | ((u32)f2bf(b) << 16);
}

__device__ __forceinline__ void gload_lds16(const void* g, void* l) {
  __builtin_amdgcn_global_load_lds(
      (__attribute__((address_space(1))) void*)g,
      (__attribute__((address_space(3))) void*)l, 16, 0, 0);
}

// ---------------------------------------------------------------------------
__global__ __launch_bounds__(256) void cvt_bf16(const float* __restrict__ src,
                                                u16* __restrict__ dst, int n4) {
  int i = blockIdx.x * 256 + threadIdx.x;
  if (i < n4) {
    float4 f = ((const float4*)src)[i];
    uint2 p;
    p.x = pack2bf(f.x, f.y);
    p.y = pack2bf(f.z, f.w);
    ((uint2*)dst)[i] = p;
  }
}

// ---------------------------------------------------------------------------
// 256x256-tile bf16 GEMM, BK=64, K=768 (12 K-tiles), B^T weights.
// (unchanged from R2)
__device__ __forceinline__ void stage8(const u16* pA, const u16* pB,
                                       char* dstA, int k0) {
#pragma unroll
  for (int i = 0; i < 4; i++)
    gload_lds16(pA + (size_t)i * 49152 + k0, dstA + i * 8192);
#pragma unroll
  for (int i = 0; i < 4; i++)
    gload_lds16(pB + (size_t)i * 49152 + k0, dstA + 32768 + i * 8192);
}

template <int MODE, int NT>
__global__ __launch_bounds__(512, 2) void gemm256(
    const u16* __restrict__ A, const u16* __restrict__ W,
    const float* __restrict__ bias, u16* __restrict__ qb, u16* __restrict__ kb,
    u16* __restrict__ vb, float* __restrict__ outf) {
  __shared__ char lds[131072];   // 2 x (32KB A + 32KB B)

  const int t = threadIdx.x;
  const int lane = t & 63, wv = t >> 6;
  const int quad = lane >> 4, l15 = lane & 15;
  const int wm = wv >> 2, wn = wv & 3;   // 2 x 4 wave grid

  // ---- bijective XCD-chunked block swizzle (m204), n-tile fastest ----
  const u32 nwg = gridDim.x;
  const u32 wg = blockIdx.x;
  const u32 qd = nwg >> 3, rm = nwg & 7;
  const u32 xcd = wg & 7, loc = wg >> 3;
  const u32 swz = (xcd < rm) ? (xcd * (qd + 1) + loc)
                             : (rm * (qd + 1) + (xcd - rm) * qd + loc);
  const int mtile = swz / NT;
  const int ntile = (int)swz - mtile * NT;
  const int m0 = mtile << 8, n0 = ntile << 8;

  // ---- staging addresses (thread-constant swizzle) ----
  const int srow = t >> 3;
  const int scol = ((t & 7) ^ (srow & 7)) << 3;   // elements
  const u16* pA = A + (size_t)(m0 + srow) * 768 + scol;
  const u16* pB = W + (size_t)(n0 + srow) * 768 + scol;
  char* sdst = lds + t * 16;

  // ---- ds_read byte offsets (within current buffer) ----
  const int swz0 = ((quad) ^ (l15 & 7)) << 4;        // k-step 0
  const int swz1 = ((4 + quad) ^ (l15 & 7)) << 4;    // k-step 1
  const int arow = (wm * 128 + l15) * 128;
  const int brow = 32768 + (wn * 64 + l15) * 128;

  f32x4 acc[8][4];
#pragma unroll
  for (int i = 0; i < 8; i++)
#pragma unroll
    for (int j = 0; j < 4; j++) acc[i][j] = (f32x4){0.f, 0.f, 0.f, 0.f};

  // ---- prologue: stage tile 0 ----
  stage8(pA, pB, sdst, 0);
  asm volatile("s_waitcnt vmcnt(0)" ::: "memory");
  __builtin_amdgcn_s_barrier();

  bf16x8 af[4][2], bfr[4][2];
  for (int kt = 0; kt < 12; ++kt) {
    char* bufc = lds + ((kt & 1) << 16);
    char* nsdst = sdst + (((kt & 1) ^ 1) << 16);
    const int k0n = (kt + 1) << 6;

    // ======== P0: A rows 0-63 + B cols 0-31; stage next tile ========
#pragma unroll
    for (int mf = 0; mf < 4; mf++) {
      af[mf][0] = *(const bf16x8*)(bufc + arow + mf * 2048 + swz0);
      af[mf][1] = *(const bf16x8*)(bufc + arow + mf * 2048 + swz1);
    }
#pragma unroll
    for (int nf = 0; nf < 2; nf++) {
      bfr[nf][0] = *(const bf16x8*)(bufc + brow + nf * 2048 + swz0);
      bfr[nf][1] = *(const bf16x8*)(bufc + brow + nf * 2048 + swz1);
    }
    if (kt < 11) stage8(pA, pB, nsdst, k0n);
    __builtin_amdgcn_s_barrier();
    asm volatile("s_waitcnt lgkmcnt(0)" ::: "memory");
    __builtin_amdgcn_s_setprio(1);
#pragma unroll
    for (int k = 0; k < 2; k++)
#pragma unroll
      for (int mf = 0; mf < 4; mf++)
#pragma unroll
        for (int nf = 0; nf < 2; nf++)
          acc[mf][nf] = __builtin_amdgcn_mfma_f32_16x16x32_bf16(
              af[mf][k], bfr[nf][k], acc[mf][nf], 0, 0, 0);
    __builtin_amdgcn_s_setprio(0);
    __builtin_amdgcn_s_barrier();

    // ======== P1: B cols 32-63 ========
#pragma unroll
    for (int nf = 2; nf < 4; nf++) {
      bfr[nf][0] = *(const bf16x8*)(bufc + brow + nf * 2048 + swz0);
      bfr[nf][1] = *(const bf16x8*)(bufc + brow + nf * 2048 + swz1);
    }
    __builtin_amdgcn_s_barrier();
    asm volatile("s_waitcnt lgkmcnt(0)" ::: "memory");
    __builtin_amdgcn_s_setprio(1);
#pragma unroll
    for (int k = 0; k < 2; k++)
#pragma unroll
      for (int mf = 0; mf < 4; mf++)
#pragma unroll
        for (int nf = 2; nf < 4; nf++)
          acc[mf][nf] = __builtin_amdgcn_mfma_f32_16x16x32_bf16(
              af[mf][k], bfr[nf][k], acc[mf][nf], 0, 0, 0);
    __builtin_amdgcn_s_setprio(0);
    __builtin_amdgcn_s_barrier();

    // ======== P2: A rows 64-127 ========
#pragma unroll
    for (int mf = 0; mf < 4; mf++) {
      af[mf][0] = *(const bf16x8*)(bufc + arow + (mf + 4) * 2048 + swz0);
      af[mf][1] = *(const bf16x8*)(bufc + arow + (mf + 4) * 2048 + swz1);
    }
    __builtin_amdgcn_s_barrier();
    asm volatile("s_waitcnt lgkmcnt(0)" ::: "memory");
    __builtin_amdgcn_s_setprio(1);
#pragma unroll
    for (int k = 0; k < 2; k++)
#pragma unroll
      for (int mf = 0; mf < 4; mf++)
#pragma unroll
        for (int nf = 0; nf < 2; nf++)
          acc[mf + 4][nf] = __builtin_amdgcn_mfma_f32_16x16x32_bf16(
              af[mf][k], bfr[nf][k], acc[mf + 4][nf], 0, 0, 0);
    __builtin_amdgcn_s_setprio(0);
    __builtin_amdgcn_s_barrier();

    // ======== P3: no ds_reads; drain next-tile staging at the end ========
    __builtin_amdgcn_s_setprio(1);
#pragma unroll
    for (int k = 0; k < 2; k++)
#pragma unroll
      for (int mf = 0; mf < 4; mf++)
#pragma unroll
        for (int nf = 2; nf < 4; nf++)
          acc[mf + 4][nf] = __builtin_amdgcn_mfma_f32_16x16x32_bf16(
              af[mf][k], bfr[nf][k], acc[mf + 4][nf], 0, 0, 0);
    __builtin_amdgcn_s_setprio(0);
    asm volatile("s_waitcnt vmcnt(0)" ::: "memory");
    __builtin_amdgcn_s_barrier();
  }

  // ---- epilogue ----
  if (MODE == 0) {
    const int which = n0 / 768;   // block-uniform (256 | 768-boundaries)
    u16* dst = (which == 0) ? qb : ((which == 1) ? kb : vb);
    const float sc = (which == 0) ? 0.125f : 1.0f;
    float bs[4];
    size_t hb[4];
#pragma unroll
    for (int nf = 0; nf < 4; nf++) {
      int n = n0 + wn * 64 + nf * 16 + l15;
      int cc = n - which * 768;
      bs[nf] = bias[n];
      hb[nf] = (size_t)(cc >> 6) * 12544 + (size_t)(cc & 63);
    }
#pragma unroll
    for (int mf = 0; mf < 8; mf++) {
#pragma unroll
      for (int r = 0; r < 4; r++) {
        int m = m0 + wm * 128 + mf * 16 + (quad << 2) + r;
        int bb = m / 196;
        int tok = m - bb * 196;
        size_t rb = (size_t)bb * 150528 + (size_t)tok * 64;
#pragma unroll
        for (int nf = 0; nf < 4; nf++)
          dst[rb + hb[nf]] = f2bf((acc[mf][nf][r] + bs[nf]) * sc);
      }
    }
  } else {
    float bs[4];
#pragma unroll
    for (int nf = 0; nf < 4; nf++)
      bs[nf] = bias[n0 + wn * 64 + nf * 16 + l15];
#pragma unroll
    for (int mf = 0; mf < 8; mf++) {
#pragma unroll
      for (int r = 0; r < 4; r++) {
        int m = m0 + wm * 128 + mf * 16 + (quad << 2) + r;
#pragma unroll
        for (int nf = 0; nf < 4; nf++)
          outf[(size_t)m * 768 + (n0 + wn * 64 + nf * 16 + l15)] =
              acc[mf][nf][r] + bs[nf];
      }
    }
  }
}

// ---------------------------------------------------------------------------
// Fused attention, swapped-operand form. One block per (b,h), 4 waves,
// wave-independent q-tiles (one barrier total, after V^T staging).
//
// S^T = mfma(K_frag, Q_frag): lane&15 = qrow, (quad,reg) = key.
//   -> row-sum = 2 shfl_xor(16,32); 1/sum lane-local at output.
// T^T = mfma(Rel_frag, Q_frag) -> per-wave LDS [28][16] f32, reads are
//   row-per-quad / col-per-lane (conflict-free within a 16-lane group).
// PV:  O^T = mfma(V^T_frag, P^T_frag); V^T from chunked Vt (contiguous
//   b128 reads); P^T built in-register: dest word w of quad q equals
//   pw2[2s+(q>>1)][w&1] shfl'd from lane l15+32(q&1)+16(w>>1).
// LDS = 26624 (Vt) + 14336 (TL) = 40960.
// NOTE: plain __launch_bounds__(256) — a min-waves arg of 3 forced VGPR=84
// and spilled everything (R3: 4x regression).
__global__ __launch_bounds__(256) void attn_fused(
    const u16* __restrict__ qbuf, const u16* __restrict__ kbuf,
    const u16* __restrict__ vbuf, const float* __restrict__ rel_h,
    const float* __restrict__ rel_w, u16* __restrict__ aout) {
  __shared__ u16 Vt[26 * 512];        // 26 chunks x [64 d][8 keys] = 26624 B
  __shared__ float TL[4][2][28][16];  // per-wave T^T (h,w): 14336 B

  const int t = threadIdx.x;
  const int bh = blockIdx.x;
  const int b = bh / 12, h = bh - b * 12;
  const int lane = t & 63, wv = t >> 6;
  const int quad = lane >> 4, l15 = lane & 15;
  const size_t base = (size_t)bh * (196 * 64);

  // ---- stage V^T (chunked) ----
  for (int c = t; c < 196 * 8; c += 256) {
    int row = c >> 3, seg = c & 7;    // key row, d-segment
    uint4 vv = *(const uint4*)(vbuf + base + row * 64 + seg * 8);
    const u16* pv8 = (const u16*)&vv;
    u16* dst = Vt + (row >> 3) * 512 + (row & 7);
#pragma unroll
    for (int e = 0; e < 8; e++) dst[(seg * 8 + e) * 8] = pv8[e];
  }
  // zero keys 196..207 (chunks 24,25 tails) so PV never multiplies NaN bits
  for (int i = t; i < 12 * 64; i += 256) {
    int k = 196 + (i >> 6), d = i & 63;
    Vt[(k >> 3) * 512 + d * 8 + (k & 7)] = 0;
  }

  // ---- rel-pos frags (8): [half h/w][ntile][ks]; used as MFMA A-operand:
  //      lane holds Rel[nt*16+l15][ks*32 + quad*8 + j] ----
  bf16x8 brl[2][2][2];
#pragma unroll
  for (int half = 0; half < 2; half++) {
    const float* relp = half ? rel_w : rel_h;
#pragma unroll
    for (int nt = 0; nt < 2; nt++) {
      int ridx = nt * 16 + l15;
      if (ridx > 26) ridx = 26;       // dup; rows >=27 never stored
#pragma unroll
      for (int ks = 0; ks < 2; ks++) {
        const float* p = relp + ridx * 64 + ks * 32 + quad * 8;
        float4 f0 = *(const float4*)p;
        float4 f1 = *(const float4*)(p + 4);
        bf16x8 r;
        r[0] = (short)f2bf(f0.x); r[1] = (short)f2bf(f0.y);
        r[2] = (short)f2bf(f0.z); r[3] = (short)f2bf(f0.w);
        r[4] = (short)f2bf(f1.x); r[5] = (short)f2bf(f1.y);
        r[6] = (short)f2bf(f1.z); r[7] = (short)f2bf(f1.w);
        brl[half][nt][ks] = r;
      }
    }
  }
  __syncthreads();   // Vt ready (only barrier)

  float (*TLh)[16] = TL[wv][0];
  float (*TLw)[16] = TL[wv][1];
  const u16* kB = kbuf + base;
  const u16* qB = qbuf + base;

  // ---- wave-independent q-tiles ----
  for (int qt = wv; qt < 13; qt += 4) {
    // Q frags: lane holds Q[qt*16 + l15][quad*8 + j] (row-clamped)
    int qrl = qt * 16 + l15;
    if (qrl > 195) qrl = 195;
    bf16x8 aq0 = *(const bf16x8*)(qB + qrl * 64 + quad * 8);
    bf16x8 aq1 = *(const bf16x8*)(qB + qrl * 64 + 32 + quad * 8);
    const int hq = qrl / 14, wq = qrl - hq * 14;  // lane-local qrow coords

    // T^T = mfma(rel, q): out col=l15=qrow, row=r27
#pragma unroll
    for (int half = 0; half < 2; half++) {
#pragma unroll
      for (int nt = 0; nt < 2; nt++) {
        f32x4 tc = (f32x4){0.f, 0.f, 0.f, 0.f};
        tc = __builtin_amdgcn_mfma_f32_16x16x32_bf16(brl[half][nt][0], aq0, tc, 0, 0, 0);
        tc = __builtin_amdgcn_mfma_f32_16x16x32_bf16(brl[half][nt][1], aq1, tc, 0, 0, 0);
#pragma unroll
        for (int r = 0; r < 4; r++) {
          int r27 = nt * 16 + quad * 4 + r;
          if (r27 < 27) TL[wv][half][r27][l15] = tc[r];
        }
      }
    }

    // pass 1: S^T tiles + bias + exp; P kept in regs as bf16 pairs.
    // pw2[kt][w] = pack(P[key=kt*16+quad*4+2w], P[key+1]) for this lane's qrow.
    u32 pw2[13][2];
    float sm = 0.f;
#pragma unroll
    for (int kt = 0; kt < 13; kt++) {
      int keyl = kt * 16 + l15;
      int keyc = (keyl > 195) ? 195 : keyl;
      bf16x8 bk0 = *(const bf16x8*)(kB + keyc * 64 + quad * 8);
      bf16x8 bk1 = *(const bf16x8*)(kB + keyc * 64 + 32 + quad * 8);
      f32x4 s = (f32x4){0.f, 0.f, 0.f, 0.f};
      s = __builtin_amdgcn_mfma_f32_16x16x32_bf16(bk0, aq0, s, 0, 0, 0);
      s = __builtin_amdgcn_mfma_f32_16x16x32_bf16(bk1, aq1, s, 0, 0, 0);
      const int key0 = kt * 16 + quad * 4;
      const int hk0 = key0 / 14, wk0 = key0 - 14 * hk0;
      const bool valid = (kt < 12) || (quad == 0);
      float pr[4];
#pragma unroll
      for (int r = 0; r < 4; r++) {
        int cr = (wk0 + r >= 14) ? 1 : 0;
        int hk = hk0 + cr, wk = wk0 + r - 14 * cr;
        float v = s[r] + TLh[hq - hk + 13][l15] + TLw[wq - wk + 13][l15];
        float p = valid ? __expf(v) : 0.f;
        pr[r] = p;
        sm += p;
      }
      pw2[kt][0] = pack2bf(pr[0], pr[1]);
      pw2[kt][1] = pack2bf(pr[2], pr[3]);
    }
    sm += __shfl_xor(sm, 16, 64);
    sm += __shfl_xor(sm, 32, 64);
    const float inv = 1.0f / sm;

    // PV: O^T = mfma(V^T, P^T). 7 steps of 32 keys; step 6 half-masked.
    f32x4 oacc[4];
#pragma unroll
    for (int dt = 0; dt < 4; dt++) oacc[dt] = (f32x4){0.f, 0.f, 0.f, 0.f};
    const int srcA = l15 + ((quad & 1) << 5);
    const bool hi = (quad >> 1) != 0;
#pragma unroll
    for (int st = 0; st < 7; st++) {
      u32 w0, w1, w2, w3;
      if (st < 6) {
        u32 a0 = __shfl(pw2[2 * st][0], srcA), b0 = __shfl(pw2[2 * st + 1][0], srcA);
        u32 a1 = __shfl(pw2[2 * st][1], srcA), b1 = __shfl(pw2[2 * st + 1][1], srcA);
        u32 a2 = __shfl(pw2[2 * st][0], srcA + 16), b2 = __shfl(pw2[2 * st + 1][0], srcA + 16);
        u32 a3 = __shfl(pw2[2 * st][1], srcA + 16), b3 = __shfl(pw2[2 * st + 1][1], srcA + 16);
        w0 = hi ? b0 : a0; w1 = hi ? b1 : a1;
        w2 = hi ? b2 : a2; w3 = hi ? b3 : a3;
      } else {
        u32 a0 = __shfl(pw2[12][0], srcA);
        u32 a1 = __shfl(pw2[12][1], srcA);
        u32 a2 = __shfl(pw2[12][0], srcA + 16);
        u32 a3 = __shfl(pw2[12][1], srcA + 16);
        w0 = hi ? 0u : a0; w1 = hi ? 0u : a1;
        w2 = hi ? 0u : a2; w3 = hi ? 0u : a3;
      }
      u32x4 pbw = (u32x4){w0, w1, w2, w3};
      bf16x8 pb = __builtin_bit_cast(bf16x8, pbw);
      const bool mvalid = (st < 6) || (quad < 2);
#pragma unroll
      for (int dt = 0; dt < 4; dt++) {
        bf16x8 av = (bf16x8){0, 0, 0, 0, 0, 0, 0, 0};
        if (mvalid)
          av = *(const bf16x8*)(Vt + (st * 4 + quad) * 512 + (dt * 16 + l15) * 8);
        oacc[dt] = __builtin_amdgcn_mfma_f32_16x16x32_bf16(av, pb, oacc[dt], 0, 0, 0);
      }
    }

    // normalize + store: lane covers d = dt*16 + quad*4 + {0..3} at its qrow
    const int qrow = qt * 16 + l15;
    if (qrow < 196) {
      u16* op = aout + ((size_t)(b * 196 + qrow) * 12 + h) * 64;
#pragma unroll
      for (int dt = 0; dt < 4; dt++) {
        uint2 stv;
        stv.x = pack2bf(oacc[dt][0] * inv, oacc[dt][1] * inv);
        stv.y = pack2bf(oacc[dt][2] * inv, oacc[dt][3] * inv);
        *(uint2*)(op + dt * 16 + quad * 4) = stv;
      }
    }
  }
}

// ---------------------------------------------------------------------------
extern "C" void kernel_launch(void* const* d_in, const int* in_sizes, int n_in,
                              void* d_out, int out_size, void* d_ws, size_t ws_size,
                              hipStream_t stream) {
  (void)in_sizes; (void)n_in; (void)out_size; (void)ws_size;
  const float* x      = (const float*)d_in[0];
  const float* qkv_w  = (const float*)d_in[1];
  const float* qkv_b  = (const float*)d_in[2];
  const float* rel_h  = (const float*)d_in[3];
  const float* rel_w  = (const float*)d_in[4];
  const float* proj_w = (const float*)d_in[5];
  const float* proj_b = (const float*)d_in[6];
  float* out = (float*)d_out;

  char* ws = (char*)d_ws;
  u16* xbf  = (u16*)(ws);              // aliased: x_bf16, then attn_out
  u16* qbuf = (u16*)(ws + 77070336);
  u16* kbuf = (u16*)(ws + 154140672);
  u16* vbuf = (u16*)(ws + 231211008);
  u16* wqb  = (u16*)(ws + 308281344);
  u16* wpb  = (u16*)(ws + 311820288);

  cvt_bf16<<<37632, 256, 0, stream>>>(x, xbf, 38535168 / 4);
  cvt_bf16<<<1728, 256, 0, stream>>>(qkv_w, wqb, 1769472 / 4);
  cvt_bf16<<<576, 256, 0, stream>>>(proj_w, wpb, 589824 / 4);

  // QKV: M=50176 (196 tiles), N=2304 (9 tiles), K=768
  gemm256<0, 9><<<1764, 512, 0, stream>>>(xbf, wqb, qkv_b, qbuf, kbuf, vbuf,
                                          nullptr);
  attn_fused<<<3072, 256, 0, stream>>>(qbuf, kbuf, vbuf, rel_h, rel_w, xbf);
  // proj: N=768 (3 tiles)
  gemm256<1, 3><<<588, 512, 0, stream>>>(xbf, wpb, proj_b, nullptr, nullptr,
                                         nullptr, out);
}

// Round 4
// 846.325 us; speedup vs baseline: 2.0172x; 1.1713x over previous
//
#include <hip/hip_runtime.h>
#include <stdint.h>

// ============================================================================
// Windowed attention (SAM-style), MI355X gfx950.
// B=256, N=196 (14x14), C=768, 12 heads x 64.
// R2: GEMMs = 256x256-tile 8-wave double-buffered 8-phase (unchanged).
// R5: attn = swapped-operand, ONLINE fusion of score-pass and PV:
//     pw2[13][2] (26 VGPR live across both passes) was spilled by the
//     allocator in R4 (VGPR=256, +188MB scratch WRITE). Now each 32-key
//     step computes scores+exp and immediately shfl-transposes into the
//     PV MFMA -> live P state = 4 regs. Also: Vt staging writes rotated
//     (ee=(e+seg)&7) to break the 8-way bank conflict.
// ============================================================================

typedef __attribute__((ext_vector_type(8))) short bf16x8;   // 8 bf16 = 4 VGPRs
typedef __attribute__((ext_vector_type(4))) float f32x4;
typedef __attribute__((ext_vector_type(4))) unsigned int u32x4;
typedef unsigned short u16;
typedef unsigned int u32;

__device__ __forceinline__ u16 f2bf(float f) {
  u32 x = __float_as_uint(f);
  x += 0x7fffu + ((x >> 16) & 1u);   // round-to-nearest-even
  return (u16)(x >> 16);
}

__device__ __forceinline__ u32 pack2bf(float a, float b) {
  return (u32)f2bf(a) | ((u32)f2bf(b) << 16);
}

__device__ __forceinline__ void gload_lds16(const void* g, void* l) {
  __builtin_amdgcn_global_load_lds(
      (__attribute__((address_space(1))) void*)g,
      (__attribute__((address_space(3))) void*)l, 16, 0, 0);
}

// ---------------------------------------------------------------------------
__global__ __launch_bounds__(256) void cvt_bf16(const float* __restrict__ src,
                                                u16* __restrict__ dst, int n4) {
  int i = blockIdx.x * 256 + threadIdx.x;
  if (i < n4) {
    float4 f = ((const float4*)src)[i];
    uint2 p;
    p.x = pack2bf(f.x, f.y);
    p.y = pack2bf(f.z, f.w);
    ((uint2*)dst)[i] = p;
  }
}

// ---------------------------------------------------------------------------
// 256x256-tile bf16 GEMM, BK=64, K=768 (12 K-tiles), B^T weights.
// (unchanged from R2)
__device__ __forceinline__ void stage8(const u16* pA, const u16* pB,
                                       char* dstA, int k0) {
#pragma unroll
  for (int i = 0; i < 4; i++)
    gload_lds16(pA + (size_t)i * 49152 + k0, dstA + i * 8192);
#pragma unroll
  for (int i = 0; i < 4; i++)
    gload_lds16(pB + (size_t)i * 49152 + k0, dstA + 32768 + i * 8192);
}

template <int MODE, int NT>
__global__ __launch_bounds__(512, 2) void gemm256(
    const u16* __restrict__ A, const u16* __restrict__ W,
    const float* __restrict__ bias, u16* __restrict__ qb, u16* __restrict__ kb,
    u16* __restrict__ vb, float* __restrict__ outf) {
  __shared__ char lds[131072];   // 2 x (32KB A + 32KB B)

  const int t = threadIdx.x;
  const int lane = t & 63, wv = t >> 6;
  const int quad = lane >> 4, l15 = lane & 15;
  const int wm = wv >> 2, wn = wv & 3;   // 2 x 4 wave grid

  // ---- bijective XCD-chunked block swizzle (m204), n-tile fastest ----
  const u32 nwg = gridDim.x;
  const u32 wg = blockIdx.x;
  const u32 qd = nwg >> 3, rm = nwg & 7;
  const u32 xcd = wg & 7, loc = wg >> 3;
  const u32 swz = (xcd < rm) ? (xcd * (qd + 1) + loc)
                             : (rm * (qd + 1) + (xcd - rm) * qd + loc);
  const int mtile = swz / NT;
  const int ntile = (int)swz - mtile * NT;
  const int m0 = mtile << 8, n0 = ntile << 8;

  // ---- staging addresses (thread-constant swizzle) ----
  const int srow = t >> 3;
  const int scol = ((t & 7) ^ (srow & 7)) << 3;   // elements
  const u16* pA = A + (size_t)(m0 + srow) * 768 + scol;
  const u16* pB = W + (size_t)(n0 + srow) * 768 + scol;
  char* sdst = lds + t * 16;

  // ---- ds_read byte offsets (within current buffer) ----
  const int swz0 = ((quad) ^ (l15 & 7)) << 4;        // k-step 0
  const int swz1 = ((4 + quad) ^ (l15 & 7)) << 4;    // k-step 1
  const int arow = (wm * 128 + l15) * 128;
  const int brow = 32768 + (wn * 64 + l15) * 128;

  f32x4 acc[8][4];
#pragma unroll
  for (int i = 0; i < 8; i++)
#pragma unroll
    for (int j = 0; j < 4; j++) acc[i][j] = (f32x4){0.f, 0.f, 0.f, 0.f};

  // ---- prologue: stage tile 0 ----
  stage8(pA, pB, sdst, 0);
  asm volatile("s_waitcnt vmcnt(0)" ::: "memory");
  __builtin_amdgcn_s_barrier();

  bf16x8 af[4][2], bfr[4][2];
  for (int kt = 0; kt < 12; ++kt) {
    char* bufc = lds + ((kt & 1) << 16);
    char* nsdst = sdst + (((kt & 1) ^ 1) << 16);
    const int k0n = (kt + 1) << 6;

    // ======== P0: A rows 0-63 + B cols 0-31; stage next tile ========
#pragma unroll
    for (int mf = 0; mf < 4; mf++) {
      af[mf][0] = *(const bf16x8*)(bufc + arow + mf * 2048 + swz0);
      af[mf][1] = *(const bf16x8*)(bufc + arow + mf * 2048 + swz1);
    }
#pragma unroll
    for (int nf = 0; nf < 2; nf++) {
      bfr[nf][0] = *(const bf16x8*)(bufc + brow + nf * 2048 + swz0);
      bfr[nf][1] = *(const bf16x8*)(bufc + brow + nf * 2048 + swz1);
    }
    if (kt < 11) stage8(pA, pB, nsdst, k0n);
    __builtin_amdgcn_s_barrier();
    asm volatile("s_waitcnt lgkmcnt(0)" ::: "memory");
    __builtin_amdgcn_s_setprio(1);
#pragma unroll
    for (int k = 0; k < 2; k++)
#pragma unroll
      for (int mf = 0; mf < 4; mf++)
#pragma unroll
        for (int nf = 0; nf < 2; nf++)
          acc[mf][nf] = __builtin_amdgcn_mfma_f32_16x16x32_bf16(
              af[mf][k], bfr[nf][k], acc[mf][nf], 0, 0, 0);
    __builtin_amdgcn_s_setprio(0);
    __builtin_amdgcn_s_barrier();

    // ======== P1: B cols 32-63 ========
#pragma unroll
    for (int nf = 2; nf < 4; nf++) {
      bfr[nf][0] = *(const bf16x8*)(bufc + brow + nf * 2048 + swz0);
      bfr[nf][1] = *(const bf16x8*)(bufc + brow + nf * 2048 + swz1);
    }
    __builtin_amdgcn_s_barrier();
    asm volatile("s_waitcnt lgkmcnt(0)" ::: "memory");
    __builtin_amdgcn_s_setprio(1);
#pragma unroll
    for (int k = 0; k < 2; k++)
#pragma unroll
      for (int mf = 0; mf < 4; mf++)
#pragma unroll
        for (int nf = 2; nf < 4; nf++)
          acc[mf][nf] = __builtin_amdgcn_mfma_f32_16x16x32_bf16(
              af[mf][k], bfr[nf][k], acc[mf][nf], 0, 0, 0);
    __builtin_amdgcn_s_setprio(0);
    __builtin_amdgcn_s_barrier();

    // ======== P2: A rows 64-127 ========
#pragma unroll
    for (int mf = 0; mf < 4; mf++) {
      af[mf][0] = *(const bf16x8*)(bufc + arow + (mf + 4) * 2048 + swz0);
      af[mf][1] = *(const bf16x8*)(bufc + arow + (mf + 4) * 2048 + swz1);
    }
    __builtin_amdgcn_s_barrier();
    asm volatile("s_waitcnt lgkmcnt(0)" ::: "memory");
    __builtin_amdgcn_s_setprio(1);
#pragma unroll
    for (int k = 0; k < 2; k++)
#pragma unroll
      for (int mf = 0; mf < 4; mf++)
#pragma unroll
        for (int nf = 0; nf < 2; nf++)
          acc[mf + 4][nf] = __builtin_amdgcn_mfma_f32_16x16x32_bf16(
              af[mf][k], bfr[nf][k], acc[mf + 4][nf], 0, 0, 0);
    __builtin_amdgcn_s_setprio(0);
    __builtin_amdgcn_s_barrier();

    // ======== P3: no ds_reads; drain next-tile staging at the end ========
    __builtin_amdgcn_s_setprio(1);
#pragma unroll
    for (int k = 0; k < 2; k++)
#pragma unroll
      for (int mf = 0; mf < 4; mf++)
#pragma unroll
        for (int nf = 2; nf < 4; nf++)
          acc[mf + 4][nf] = __builtin_amdgcn_mfma_f32_16x16x32_bf16(
              af[mf][k], bfr[nf][k], acc[mf + 4][nf], 0, 0, 0);
    __builtin_amdgcn_s_setprio(0);
    asm volatile("s_waitcnt vmcnt(0)" ::: "memory");
    __builtin_amdgcn_s_barrier();
  }

  // ---- epilogue ----
  if (MODE == 0) {
    const int which = n0 / 768;   // block-uniform (256 | 768-boundaries)
    u16* dst = (which == 0) ? qb : ((which == 1) ? kb : vb);
    const float sc = (which == 0) ? 0.125f : 1.0f;
    float bs[4];
    size_t hb[4];
#pragma unroll
    for (int nf = 0; nf < 4; nf++) {
      int n = n0 + wn * 64 + nf * 16 + l15;
      int cc = n - which * 768;
      bs[nf] = bias[n];
      hb[nf] = (size_t)(cc >> 6) * 12544 + (size_t)(cc & 63);
    }
#pragma unroll
    for (int mf = 0; mf < 8; mf++) {
#pragma unroll
      for (int r = 0; r < 4; r++) {
        int m = m0 + wm * 128 + mf * 16 + (quad << 2) + r;
        int bb = m / 196;
        int tok = m - bb * 196;
        size_t rb = (size_t)bb * 150528 + (size_t)tok * 64;
#pragma unroll
        for (int nf = 0; nf < 4; nf++)
          dst[rb + hb[nf]] = f2bf((acc[mf][nf][r] + bs[nf]) * sc);
      }
    }
  } else {
    float bs[4];
#pragma unroll
    for (int nf = 0; nf < 4; nf++)
      bs[nf] = bias[n0 + wn * 64 + nf * 16 + l15];
#pragma unroll
    for (int mf = 0; mf < 8; mf++) {
#pragma unroll
      for (int r = 0; r < 4; r++) {
        int m = m0 + wm * 128 + mf * 16 + (quad << 2) + r;
#pragma unroll
        for (int nf = 0; nf < 4; nf++)
          outf[(size_t)m * 768 + (n0 + wn * 64 + nf * 16 + l15)] =
              acc[mf][nf][r] + bs[nf];
      }
    }
  }
}

// ---------------------------------------------------------------------------
// Fused attention, swapped-operand, ONLINE score->PV fusion.
// One block per (b,h), 4 waves, wave-independent q-tiles (one barrier).
//
// S^T = mfma(K, Q): lane&15 = qrow, (quad,reg) = key.
// Per 32-key step: compute 2x16-key score frags, exp, accumulate sm,
// shfl-transpose the 4 packed u32 into the P^T B-frag, 4 PV MFMAs.
// No pw2 array -> no spill (R4: VGPR=256, 188MB scratch writes).
// Main loop st=0..5 is mask-free (keys <= 191 < 196); kt=12 tail explicit.
// LDS = 26624 (Vt) + 14336 (TL) = 40960 -> 4 blocks/CU.
__global__ __launch_bounds__(256) void attn_fused(
    const u16* __restrict__ qbuf, const u16* __restrict__ kbuf,
    const u16* __restrict__ vbuf, const float* __restrict__ rel_h,
    const float* __restrict__ rel_w, u16* __restrict__ aout) {
  __shared__ u16 Vt[26 * 512];        // 26 chunks x [64 d][8 keys] = 26624 B
  __shared__ float TL[4][2][28][16];  // per-wave T^T (h,w): 14336 B

  const int t = threadIdx.x;
  const int bh = blockIdx.x;
  const int b = bh / 12, h = bh - b * 12;
  const int lane = t & 63, wv = t >> 6;
  const int quad = lane >> 4, l15 = lane & 15;
  const size_t base = (size_t)bh * (196 * 64);

  // ---- stage V^T (chunked); write order rotated by seg so the 8 seg-lanes
  //      of a row-group hit 8 distinct banks (was 8-way conflicted) ----
  for (int c = t; c < 196 * 8; c += 256) {
    int row = c >> 3, seg = c & 7;    // key row, d-segment
    uint4 vv = *(const uint4*)(vbuf + base + row * 64 + seg * 8);
    const u16* pv8 = (const u16*)&vv;
    u16* dst = Vt + (row >> 3) * 512 + (row & 7);
#pragma unroll
    for (int e = 0; e < 8; e++) {
      int ee = (e + seg) & 7;
      dst[(seg * 8 + ee) * 8] = pv8[ee];
    }
  }
  // zero keys 196..207 (chunks 24,25 tails) so PV never multiplies NaN bits
  for (int i = t; i < 12 * 64; i += 256) {
    int k = 196 + (i >> 6), d = i & 63;
    Vt[(k >> 3) * 512 + d * 8 + (k & 7)] = 0;
  }

  // ---- rel-pos frags (8): [half h/w][ntile][ks]; MFMA A-operand:
  //      lane holds Rel[nt*16+l15][ks*32 + quad*8 + j] ----
  bf16x8 brl[2][2][2];
#pragma unroll
  for (int half = 0; half < 2; half++) {
    const float* relp = half ? rel_w : rel_h;
#pragma unroll
    for (int nt = 0; nt < 2; nt++) {
      int ridx = nt * 16 + l15;
      if (ridx > 26) ridx = 26;       // dup; rows >=27 never stored
#pragma unroll
      for (int ks = 0; ks < 2; ks++) {
        const float* p = relp + ridx * 64 + ks * 32 + quad * 8;
        float4 f0 = *(const float4*)p;
        float4 f1 = *(const float4*)(p + 4);
        bf16x8 r;
        r[0] = (short)f2bf(f0.x); r[1] = (short)f2bf(f0.y);
        r[2] = (short)f2bf(f0.z); r[3] = (short)f2bf(f0.w);
        r[4] = (short)f2bf(f1.x); r[5] = (short)f2bf(f1.y);
        r[6] = (short)f2bf(f1.z); r[7] = (short)f2bf(f1.w);
        brl[half][nt][ks] = r;
      }
    }
  }
  __syncthreads();   // Vt ready (only barrier)

  float (*TLh)[16] = TL[wv][0];
  float (*TLw)[16] = TL[wv][1];
  const u16* kB = kbuf + base;
  const u16* qB = qbuf + base;

  // ---- wave-independent q-tiles ----
  for (int qt = wv; qt < 13; qt += 4) {
    // Q frags: lane holds Q[qt*16 + l15][quad*8 + j] (row-clamped)
    int qrl = qt * 16 + l15;
    if (qrl > 195) qrl = 195;
    bf16x8 aq0 = *(const bf16x8*)(qB + qrl * 64 + quad * 8);
    bf16x8 aq1 = *(const bf16x8*)(qB + qrl * 64 + 32 + quad * 8);
    const int hq = qrl / 14, wq = qrl - hq * 14;  // lane-local qrow coords

    // T^T = mfma(rel, q): out col=l15=qrow, row=r27
#pragma unroll
    for (int half = 0; half < 2; half++) {
#pragma unroll
      for (int nt = 0; nt < 2; nt++) {
        f32x4 tc = (f32x4){0.f, 0.f, 0.f, 0.f};
        tc = __builtin_amdgcn_mfma_f32_16x16x32_bf16(brl[half][nt][0], aq0, tc, 0, 0, 0);
        tc = __builtin_amdgcn_mfma_f32_16x16x32_bf16(brl[half][nt][1], aq1, tc, 0, 0, 0);
#pragma unroll
        for (int r = 0; r < 4; r++) {
          int r27 = nt * 16 + quad * 4 + r;
          if (r27 < 27) TL[wv][half][r27][l15] = tc[r];
        }
      }
    }

    // ---- online score+PV loop: 6 steps of 32 keys (all mask-free) ----
    f32x4 oacc[4];
#pragma unroll
    for (int dt = 0; dt < 4; dt++) oacc[dt] = (f32x4){0.f, 0.f, 0.f, 0.f};
    float sm = 0.f;
    const int srcA = l15 + ((quad & 1) << 5);
    const bool hi = (quad >> 1) != 0;

#pragma unroll 2
    for (int st = 0; st < 6; st++) {
      u32 pw[2][2];
#pragma unroll
      for (int u = 0; u < 2; u++) {
        const int kt = st * 2 + u;
        const int keyl = kt * 16 + l15;            // <= 191: no clamp
        bf16x8 bk0 = *(const bf16x8*)(kB + keyl * 64 + quad * 8);
        bf16x8 bk1 = *(const bf16x8*)(kB + keyl * 64 + 32 + quad * 8);
        f32x4 s = (f32x4){0.f, 0.f, 0.f, 0.f};
        s = __builtin_amdgcn_mfma_f32_16x16x32_bf16(bk0, aq0, s, 0, 0, 0);
        s = __builtin_amdgcn_mfma_f32_16x16x32_bf16(bk1, aq1, s, 0, 0, 0);
        const int key0 = kt * 16 + quad * 4;       // <= 188
        const int hk0 = key0 / 14, wk0 = key0 - 14 * hk0;
        float pr[4];
#pragma unroll
        for (int r = 0; r < 4; r++) {
          int cr = (wk0 + r >= 14) ? 1 : 0;
          int hk = hk0 + cr, wk = wk0 + r - 14 * cr;
          float v = s[r] + TLh[hq - hk + 13][l15] + TLw[wq - wk + 13][l15];
          float p = __expf(v);
          pr[r] = p;
          sm += p;
        }
        pw[u][0] = pack2bf(pr[0], pr[1]);
        pw[u][1] = pack2bf(pr[2], pr[3]);
      }
      // transpose P (4 u32/lane) into PV B-frag via 8 shfl + 4 select
      u32 a0 = __shfl(pw[0][0], srcA),      b0 = __shfl(pw[1][0], srcA);
      u32 a1 = __shfl(pw[0][1], srcA),      b1 = __shfl(pw[1][1], srcA);
      u32 a2 = __shfl(pw[0][0], srcA + 16), b2 = __shfl(pw[1][0], srcA + 16);
      u32 a3 = __shfl(pw[0][1], srcA + 16), b3 = __shfl(pw[1][1], srcA + 16);
      u32x4 pbw = (u32x4){hi ? b0 : a0, hi ? b1 : a1, hi ? b2 : a2, hi ? b3 : a3};
      bf16x8 pb = __builtin_bit_cast(bf16x8, pbw);
#pragma unroll
      for (int dt = 0; dt < 4; dt++) {
        bf16x8 av = *(const bf16x8*)(Vt + (st * 4 + quad) * 512 + (dt * 16 + l15) * 8);
        oacc[dt] = __builtin_amdgcn_mfma_f32_16x16x32_bf16(av, pb, oacc[dt], 0, 0, 0);
      }
    }

    // ---- tail: kt = 12 (keys 192..195 valid; rest masked) ----
    {
      const int keyl = 192 + l15;
      const int keyc = (keyl > 195) ? 195 : keyl;
      bf16x8 bk0 = *(const bf16x8*)(kB + keyc * 64 + quad * 8);
      bf16x8 bk1 = *(const bf16x8*)(kB + keyc * 64 + 32 + quad * 8);
      f32x4 s = (f32x4){0.f, 0.f, 0.f, 0.f};
      s = __builtin_amdgcn_mfma_f32_16x16x32_bf16(bk0, aq0, s, 0, 0, 0);
      s = __builtin_amdgcn_mfma_f32_16x16x32_bf16(bk1, aq1, s, 0, 0, 0);
      const int key0 = 192 + quad * 4;
      const int hk0 = key0 / 14, wk0 = key0 - 14 * hk0;
      const bool valid = (quad == 0);
      float pr[4];
#pragma unroll
      for (int r = 0; r < 4; r++) {
        int cr = (wk0 + r >= 14) ? 1 : 0;
        int hk = hk0 + cr, wk = wk0 + r - 14 * cr;
        int ih = hq - hk + 13; ih = ih < 0 ? 0 : ih;
        int iw = wq - wk + 13; iw = iw < 0 ? 0 : iw;
        float v = s[r] + TLh[ih][l15] + TLw[iw][l15];
        float p = valid ? __expf(v) : 0.f;
        pr[r] = p;
        sm += p;
      }
      u32 pw0 = pack2bf(pr[0], pr[1]);
      u32 pw1 = pack2bf(pr[2], pr[3]);
      const int srcA = l15 + ((quad & 1) << 5);
      const bool hi = (quad >> 1) != 0;
      u32 a0 = __shfl(pw0, srcA);
      u32 a1 = __shfl(pw1, srcA);
      u32 a2 = __shfl(pw0, srcA + 16);
      u32 a3 = __shfl(pw1, srcA + 16);
      u32x4 pbw = (u32x4){hi ? 0u : a0, hi ? 0u : a1, hi ? 0u : a2, hi ? 0u : a3};
      bf16x8 pb = __builtin_bit_cast(bf16x8, pbw);
#pragma unroll
      for (int dt = 0; dt < 4; dt++) {
        bf16x8 av = (bf16x8){0, 0, 0, 0, 0, 0, 0, 0};
        if (quad < 2)
          av = *(const bf16x8*)(Vt + (24 + quad) * 512 + (dt * 16 + l15) * 8);
        oacc[dt] = __builtin_amdgcn_mfma_f32_16x16x32_bf16(av, pb, oacc[dt], 0, 0, 0);
      }
    }

    // row sum across the 4 lane-groups holding this qrow, then normalize
    sm += __shfl_xor(sm, 16, 64);
    sm += __shfl_xor(sm, 32, 64);
    const float inv = 1.0f / sm;

    const int qrow = qt * 16 + l15;
    if (qrow < 196) {
      u16* op = aout + ((size_t)(b * 196 + qrow) * 12 + h) * 64;
#pragma unroll
      for (int dt = 0; dt < 4; dt++) {
        uint2 stv;
        stv.x = pack2bf(oacc[dt][0] * inv, oacc[dt][1] * inv);
        stv.y = pack2bf(oacc[dt][2] * inv, oacc[dt][3] * inv);
        *(uint2*)(op + dt * 16 + quad * 4) = stv;
      }
    }
  }
}

// ---------------------------------------------------------------------------
extern "C" void kernel_launch(void* const* d_in, const int* in_sizes, int n_in,
                              void* d_out, int out_size, void* d_ws, size_t ws_size,
                              hipStream_t stream) {
  (void)in_sizes; (void)n_in; (void)out_size; (void)ws_size;
  const float* x      = (const float*)d_in[0];
  const float* qkv_w  = (const float*)d_in[1];
  const float* qkv_b  = (const float*)d_in[2];
  const float* rel_h  = (const float*)d_in[3];
  const float* rel_w  = (const float*)d_in[4];
  const float* proj_w = (const float*)d_in[5];
  const float* proj_b = (const float*)d_in[6];
  float* out = (float*)d_out;

  char* ws = (char*)d_ws;
  u16* xbf  = (u16*)(ws);              // aliased: x_bf16, then attn_out
  u16* qbuf = (u16*)(ws + 77070336);
  u16* kbuf = (u16*)(ws + 154140672);
  u16* vbuf = (u16*)(ws + 231211008);
  u16* wqb  = (u16*)(ws + 308281344);
  u16* wpb  = (u16*)(ws + 311820288);

  cvt_bf16<<<37632, 256, 0, stream>>>(x, xbf, 38535168 / 4);
  cvt_bf16<<<1728, 256, 0, stream>>>(qkv_w, wqb, 1769472 / 4);
  cvt_bf16<<<576, 256, 0, stream>>>(proj_w, wpb, 589824 / 4);

  // QKV: M=50176 (196 tiles), N=2304 (9 tiles), K=768
  gemm256<0, 9><<<1764, 512, 0, stream>>>(xbf, wqb, qkv_b, qbuf, kbuf, vbuf,
                                          nullptr);
  attn_fused<<<3072, 256, 0, stream>>>(qbuf, kbuf, vbuf, rel_h, rel_w, xbf);
  // proj: N=768 (3 tiles)
  gemm256<1, 3><<<588, 512, 0, stream>>>(xbf, wpb, proj_b, nullptr, nullptr,
                                         nullptr, out);
}

// Round 5
// 798.823 us; speedup vs baseline: 2.1372x; 1.0595x over previous
//
#include <hip/hip_runtime.h>
#include <stdint.h>

// ============================================================================
// Windowed attention (SAM-style), MI355X gfx950.
// B=256, N=196 (14x14), C=768, 12 heads x 64.
// R2: GEMMs = 256x256-tile 8-wave double-buffered 8-phase (unchanged).
// R6: attn = R5 online swapped-operand structure + DUAL q-tile ILP:
//     each wave processes q-tile pair (2p, 2p+1) with two independent
//     score->exp->pack->transpose->PV chains sharing K loads and Vt reads.
//     R5 was latency-bound (MfmaUtil 5.6 / VALU 35 / HBM 8.7 / occ 19.5,
//     VGPR only 92): one serial chain per wave left every pipe idle.
//     TLh windowed to 17 rows (hq-h0<=3 for a 32-row pair), pads to 33 cols.
//     LDS = 26624 + 8976 + 14784 = 50384 -> 3 blocks/CU.
// ============================================================================

typedef __attribute__((ext_vector_type(8))) short bf16x8;   // 8 bf16 = 4 VGPRs
typedef __attribute__((ext_vector_type(4))) float f32x4;
typedef __attribute__((ext_vector_type(4))) unsigned int u32x4;
typedef unsigned short u16;
typedef unsigned int u32;

__device__ __forceinline__ u16 f2bf(float f) {
  u32 x = __float_as_uint(f);
  x += 0x7fffu + ((x >> 16) & 1u);   // round-to-nearest-even
  return (u16)(x >> 16);
}

__device__ __forceinline__ u32 pack2bf(float a, float b) {
  return (u32)f2bf(a) | ((u32)f2bf(b) << 16);
}

__device__ __forceinline__ void gload_lds16(const void* g, void* l) {
  __builtin_amdgcn_global_load_lds(
      (__attribute__((address_space(1))) void*)g,
      (__attribute__((address_space(3))) void*)l, 16, 0, 0);
}

// ---------------------------------------------------------------------------
__global__ __launch_bounds__(256) void cvt_bf16(const float* __restrict__ src,
                                                u16* __restrict__ dst, int n4) {
  int i = blockIdx.x * 256 + threadIdx.x;
  if (i < n4) {
    float4 f = ((const float4*)src)[i];
    uint2 p;
    p.x = pack2bf(f.x, f.y);
    p.y = pack2bf(f.z, f.w);
    ((uint2*)dst)[i] = p;
  }
}

// ---------------------------------------------------------------------------
// 256x256-tile bf16 GEMM, BK=64, K=768 (12 K-tiles), B^T weights.
// (unchanged from R2)
__device__ __forceinline__ void stage8(const u16* pA, const u16* pB,
                                       char* dstA, int k0) {
#pragma unroll
  for (int i = 0; i < 4; i++)
    gload_lds16(pA + (size_t)i * 49152 + k0, dstA + i * 8192);
#pragma unroll
  for (int i = 0; i < 4; i++)
    gload_lds16(pB + (size_t)i * 49152 + k0, dstA + 32768 + i * 8192);
}

template <int MODE, int NT>
__global__ __launch_bounds__(512, 2) void gemm256(
    const u16* __restrict__ A, const u16* __restrict__ W,
    const float* __restrict__ bias, u16* __restrict__ qb, u16* __restrict__ kb,
    u16* __restrict__ vb, float* __restrict__ outf) {
  __shared__ char lds[131072];   // 2 x (32KB A + 32KB B)

  const int t = threadIdx.x;
  const int lane = t & 63, wv = t >> 6;
  const int quad = lane >> 4, l15 = lane & 15;
  const int wm = wv >> 2, wn = wv & 3;   // 2 x 4 wave grid

  // ---- bijective XCD-chunked block swizzle (m204), n-tile fastest ----
  const u32 nwg = gridDim.x;
  const u32 wg = blockIdx.x;
  const u32 qd = nwg >> 3, rm = nwg & 7;
  const u32 xcd = wg & 7, loc = wg >> 3;
  const u32 swz = (xcd < rm) ? (xcd * (qd + 1) + loc)
                             : (rm * (qd + 1) + (xcd - rm) * qd + loc);
  const int mtile = swz / NT;
  const int ntile = (int)swz - mtile * NT;
  const int m0 = mtile << 8, n0 = ntile << 8;

  // ---- staging addresses (thread-constant swizzle) ----
  const int srow = t >> 3;
  const int scol = ((t & 7) ^ (srow & 7)) << 3;   // elements
  const u16* pA = A + (size_t)(m0 + srow) * 768 + scol;
  const u16* pB = W + (size_t)(n0 + srow) * 768 + scol;
  char* sdst = lds + t * 16;

  // ---- ds_read byte offsets (within current buffer) ----
  const int swz0 = ((quad) ^ (l15 & 7)) << 4;        // k-step 0
  const int swz1 = ((4 + quad) ^ (l15 & 7)) << 4;    // k-step 1
  const int arow = (wm * 128 + l15) * 128;
  const int brow = 32768 + (wn * 64 + l15) * 128;

  f32x4 acc[8][4];
#pragma unroll
  for (int i = 0; i < 8; i++)
#pragma unroll
    for (int j = 0; j < 4; j++) acc[i][j] = (f32x4){0.f, 0.f, 0.f, 0.f};

  // ---- prologue: stage tile 0 ----
  stage8(pA, pB, sdst, 0);
  asm volatile("s_waitcnt vmcnt(0)" ::: "memory");
  __builtin_amdgcn_s_barrier();

  bf16x8 af[4][2], bfr[4][2];
  for (int kt = 0; kt < 12; ++kt) {
    char* bufc = lds + ((kt & 1) << 16);
    char* nsdst = sdst + (((kt & 1) ^ 1) << 16);
    const int k0n = (kt + 1) << 6;

    // ======== P0: A rows 0-63 + B cols 0-31; stage next tile ========
#pragma unroll
    for (int mf = 0; mf < 4; mf++) {
      af[mf][0] = *(const bf16x8*)(bufc + arow + mf * 2048 + swz0);
      af[mf][1] = *(const bf16x8*)(bufc + arow + mf * 2048 + swz1);
    }
#pragma unroll
    for (int nf = 0; nf < 2; nf++) {
      bfr[nf][0] = *(const bf16x8*)(bufc + brow + nf * 2048 + swz0);
      bfr[nf][1] = *(const bf16x8*)(bufc + brow + nf * 2048 + swz1);
    }
    if (kt < 11) stage8(pA, pB, nsdst, k0n);
    __builtin_amdgcn_s_barrier();
    asm volatile("s_waitcnt lgkmcnt(0)" ::: "memory");
    __builtin_amdgcn_s_setprio(1);
#pragma unroll
    for (int k = 0; k < 2; k++)
#pragma unroll
      for (int mf = 0; mf < 4; mf++)
#pragma unroll
        for (int nf = 0; nf < 2; nf++)
          acc[mf][nf] = __builtin_amdgcn_mfma_f32_16x16x32_bf16(
              af[mf][k], bfr[nf][k], acc[mf][nf], 0, 0, 0);
    __builtin_amdgcn_s_setprio(0);
    __builtin_amdgcn_s_barrier();

    // ======== P1: B cols 32-63 ========
#pragma unroll
    for (int nf = 2; nf < 4; nf++) {
      bfr[nf][0] = *(const bf16x8*)(bufc + brow + nf * 2048 + swz0);
      bfr[nf][1] = *(const bf16x8*)(bufc + brow + nf * 2048 + swz1);
    }
    __builtin_amdgcn_s_barrier();
    asm volatile("s_waitcnt lgkmcnt(0)" ::: "memory");
    __builtin_amdgcn_s_setprio(1);
#pragma unroll
    for (int k = 0; k < 2; k++)
#pragma unroll
      for (int mf = 0; mf < 4; mf++)
#pragma unroll
        for (int nf = 2; nf < 4; nf++)
          acc[mf][nf] = __builtin_amdgcn_mfma_f32_16x16x32_bf16(
              af[mf][k], bfr[nf][k], acc[mf][nf], 0, 0, 0);
    __builtin_amdgcn_s_setprio(0);
    __builtin_amdgcn_s_barrier();

    // ======== P2: A rows 64-127 ========
#pragma unroll
    for (int mf = 0; mf < 4; mf++) {
      af[mf][0] = *(const bf16x8*)(bufc + arow + (mf + 4) * 2048 + swz0);
      af[mf][1] = *(const bf16x8*)(bufc + arow + (mf + 4) * 2048 + swz1);
    }
    __builtin_amdgcn_s_barrier();
    asm volatile("s_waitcnt lgkmcnt(0)" ::: "memory");
    __builtin_amdgcn_s_setprio(1);
#pragma unroll
    for (int k = 0; k < 2; k++)
#pragma unroll
      for (int mf = 0; mf < 4; mf++)
#pragma unroll
        for (int nf = 0; nf < 2; nf++)
          acc[mf + 4][nf] = __builtin_amdgcn_mfma_f32_16x16x32_bf16(
              af[mf][k], bfr[nf][k], acc[mf + 4][nf], 0, 0, 0);
    __builtin_amdgcn_s_setprio(0);
    __builtin_amdgcn_s_barrier();

    // ======== P3: no ds_reads; drain next-tile staging at the end ========
    __builtin_amdgcn_s_setprio(1);
#pragma unroll
    for (int k = 0; k < 2; k++)
#pragma unroll
      for (int mf = 0; mf < 4; mf++)
#pragma unroll
        for (int nf = 2; nf < 4; nf++)
          acc[mf + 4][nf] = __builtin_amdgcn_mfma_f32_16x16x32_bf16(
              af[mf][k], bfr[nf][k], acc[mf + 4][nf], 0, 0, 0);
    __builtin_amdgcn_s_setprio(0);
    asm volatile("s_waitcnt vmcnt(0)" ::: "memory");
    __builtin_amdgcn_s_barrier();
  }

  // ---- epilogue ----
  if (MODE == 0) {
    const int which = n0 / 768;   // block-uniform (256 | 768-boundaries)
    u16* dst = (which == 0) ? qb : ((which == 1) ? kb : vb);
    const float sc = (which == 0) ? 0.125f : 1.0f;
    float bs[4];
    size_t hb[4];
#pragma unroll
    for (int nf = 0; nf < 4; nf++) {
      int n = n0 + wn * 64 + nf * 16 + l15;
      int cc = n - which * 768;
      bs[nf] = bias[n];
      hb[nf] = (size_t)(cc >> 6) * 12544 + (size_t)(cc & 63);
    }
#pragma unroll
    for (int mf = 0; mf < 8; mf++) {
#pragma unroll
      for (int r = 0; r < 4; r++) {
        int m = m0 + wm * 128 + mf * 16 + (quad << 2) + r;
        int bb = m / 196;
        int tok = m - bb * 196;
        size_t rb = (size_t)bb * 150528 + (size_t)tok * 64;
#pragma unroll
        for (int nf = 0; nf < 4; nf++)
          dst[rb + hb[nf]] = f2bf((acc[mf][nf][r] + bs[nf]) * sc);
      }
    }
  } else {
    float bs[4];
#pragma unroll
    for (int nf = 0; nf < 4; nf++)
      bs[nf] = bias[n0 + wn * 64 + nf * 16 + l15];
#pragma unroll
    for (int mf = 0; mf < 8; mf++) {
#pragma unroll
      for (int r = 0; r < 4; r++) {
        int m = m0 + wm * 128 + mf * 16 + (quad << 2) + r;
#pragma unroll
        for (int nf = 0; nf < 4; nf++)
          outf[(size_t)m * 768 + (n0 + wn * 64 + nf * 16 + l15)] =
              acc[mf][nf][r] + bs[nf];
      }
    }
  }
}

// ---------------------------------------------------------------------------
// Fused attention, swapped-operand, online score->PV, DUAL q-tile per wave.
// One block per (b,h), 4 waves, one barrier (after Vt staging).
//
// Pairing: wave wv owns pairs p = wv, wv+4 (p<7); pair p = q-tiles (2p,2p+1).
// p=6's second tile (qt=13) is fully clamped & store-masked.
// Per 32-key step: shared K loads + shared Vt reads feed TWO independent
// chains (QK mfma -> bias gather -> exp -> pack -> shfl-transpose -> PV).
// TLh windowed: for a 32-qrow pair, ih-h0 in [0,16] (17 rows); TLw 28 rows.
// Both padded to 33 cols: bank = (row+col)%32 -> <=2-way conflicts.
__global__ __launch_bounds__(256) void attn_fused(
    const u16* __restrict__ qbuf, const u16* __restrict__ kbuf,
    const u16* __restrict__ vbuf, const float* __restrict__ rel_h,
    const float* __restrict__ rel_w, u16* __restrict__ aout) {
  __shared__ u16 Vt[26 * 512];          // 26 chunks x [64 d][8 keys] = 26624 B
  __shared__ float TLh[4][17][33];      // per-wave windowed Th^T: 8976 B
  __shared__ float TLw[4][28][33];      // per-wave Tw^T: 14784 B

  const int t = threadIdx.x;
  const int bh = blockIdx.x;
  const int b = bh / 12, h = bh - b * 12;
  const int lane = t & 63, wv = t >> 6;
  const int quad = lane >> 4, l15 = lane & 15;
  const size_t base = (size_t)bh * (196 * 64);

  // ---- stage V^T (chunked); write order rotated by seg (bank-spread) ----
  for (int c = t; c < 196 * 8; c += 256) {
    int row = c >> 3, seg = c & 7;    // key row, d-segment
    uint4 vv = *(const uint4*)(vbuf + base + row * 64 + seg * 8);
    const u16* pv8 = (const u16*)&vv;
    u16* dst = Vt + (row >> 3) * 512 + (row & 7);
#pragma unroll
    for (int e = 0; e < 8; e++) {
      int ee = (e + seg) & 7;
      dst[(seg * 8 + ee) * 8] = pv8[ee];
    }
  }
  // zero keys 196..207 (chunks 24,25 tails) so PV never multiplies NaN bits
  for (int i = t; i < 12 * 64; i += 256) {
    int k = 196 + (i >> 6), d = i & 63;
    Vt[(k >> 3) * 512 + d * 8 + (k & 7)] = 0;
  }

  // ---- rel-pos frags (8): [half h/w][ntile][ks]; MFMA A-operand:
  //      lane holds Rel[nt*16+l15][ks*32 + quad*8 + j] ----
  bf16x8 brl[2][2][2];
#pragma unroll
  for (int half = 0; half < 2; half++) {
    const float* relp = half ? rel_w : rel_h;
#pragma unroll
    for (int nt = 0; nt < 2; nt++) {
      int ridx = nt * 16 + l15;
      if (ridx > 26) ridx = 26;       // dup; rows >=27 never stored
#pragma unroll
      for (int ks = 0; ks < 2; ks++) {
        const float* p = relp + ridx * 64 + ks * 32 + quad * 8;
        float4 f0 = *(const float4*)p;
        float4 f1 = *(const float4*)(p + 4);
        bf16x8 r;
        r[0] = (short)f2bf(f0.x); r[1] = (short)f2bf(f0.y);
        r[2] = (short)f2bf(f0.z); r[3] = (short)f2bf(f0.w);
        r[4] = (short)f2bf(f1.x); r[5] = (short)f2bf(f1.y);
        r[6] = (short)f2bf(f1.z); r[7] = (short)f2bf(f1.w);
        brl[half][nt][ks] = r;
      }
    }
  }
  __syncthreads();   // Vt ready (only barrier)

  const u16* kB = kbuf + base;
  const u16* qB = qbuf + base;

  // ---- dual q-tile pairs ----
  for (int p = wv; p < 7; p += 4) {
    const int qt0 = 2 * p;
    const int h0 = (32 * p) / 14;

    bf16x8 aq0[2], aq1[2];
    int hqv[2], wqv[2], hbv[2];
#pragma unroll
    for (int j = 0; j < 2; j++) {
      int qrl = (qt0 + j) * 16 + l15;
      if (qrl > 195) qrl = 195;
      aq0[j] = *(const bf16x8*)(qB + qrl * 64 + quad * 8);
      aq1[j] = *(const bf16x8*)(qB + qrl * 64 + 32 + quad * 8);
      hqv[j] = qrl / 14;
      wqv[j] = qrl - hqv[j] * 14;
      hbv[j] = hqv[j] + 13 - h0;      // read index = hbv - hk, in [0,16]
    }

    // T tables for both tiles: T^T = mfma(rel, q), col = l15 = qrow-in-tile
#pragma unroll
    for (int j = 0; j < 2; j++) {
#pragma unroll
      for (int half = 0; half < 2; half++) {
#pragma unroll
        for (int nt = 0; nt < 2; nt++) {
          f32x4 tc = (f32x4){0.f, 0.f, 0.f, 0.f};
          tc = __builtin_amdgcn_mfma_f32_16x16x32_bf16(brl[half][nt][0], aq0[j], tc, 0, 0, 0);
          tc = __builtin_amdgcn_mfma_f32_16x16x32_bf16(brl[half][nt][1], aq1[j], tc, 0, 0, 0);
#pragma unroll
          for (int r = 0; r < 4; r++) {
            int r27 = nt * 16 + quad * 4 + r;
            if (half == 0) {
              u32 ihh = (u32)(r27 - h0);
              if (ihh < 17u) TLh[wv][ihh][l15 + 16 * j] = tc[r];
            } else {
              if (r27 < 27) TLw[wv][r27][l15 + 16 * j] = tc[r];
            }
          }
        }
      }
    }

    // ---- online score+PV: 6 mask-free 32-key steps, dual chains ----
    f32x4 oacc[2][4];
#pragma unroll
    for (int j = 0; j < 2; j++)
#pragma unroll
      for (int dt = 0; dt < 4; dt++) oacc[j][dt] = (f32x4){0.f, 0.f, 0.f, 0.f};
    float sm[2] = {0.f, 0.f};
    const int srcA = l15 + ((quad & 1) << 5);
    const bool hi = (quad >> 1) != 0;

    for (int st = 0; st < 6; st++) {
      u32 pw[2][2][2];   // [j][u][word]
#pragma unroll
      for (int u = 0; u < 2; u++) {
        const int kt = st * 2 + u;
        const int keyl = kt * 16 + l15;            // <= 191: no clamp
        bf16x8 bk0 = *(const bf16x8*)(kB + keyl * 64 + quad * 8);
        bf16x8 bk1 = *(const bf16x8*)(kB + keyl * 64 + 32 + quad * 8);
        const int key0 = kt * 16 + quad * 4;       // <= 188
        const int hk0 = key0 / 14, wk0 = key0 - 14 * hk0;
#pragma unroll
        for (int j = 0; j < 2; j++) {
          f32x4 s = (f32x4){0.f, 0.f, 0.f, 0.f};
          s = __builtin_amdgcn_mfma_f32_16x16x32_bf16(bk0, aq0[j], s, 0, 0, 0);
          s = __builtin_amdgcn_mfma_f32_16x16x32_bf16(bk1, aq1[j], s, 0, 0, 0);
          float pr[4];
#pragma unroll
          for (int r = 0; r < 4; r++) {
            int cr = (wk0 + r >= 14) ? 1 : 0;
            int hk = hk0 + cr, wk = wk0 + r - 14 * cr;
            float v = s[r] + TLh[wv][hbv[j] - hk][l15 + 16 * j] +
                      TLw[wv][wqv[j] - wk + 13][l15 + 16 * j];
            float pe = __expf(v);
            pr[r] = pe;
            sm[j] += pe;
          }
          pw[j][u][0] = pack2bf(pr[0], pr[1]);
          pw[j][u][1] = pack2bf(pr[2], pr[3]);
        }
      }
      // transpose each tile's P into its PV B-frag (8 shfl + 4 sel per j)
      bf16x8 pb[2];
#pragma unroll
      for (int j = 0; j < 2; j++) {
        u32 a0 = __shfl(pw[j][0][0], srcA),      b0 = __shfl(pw[j][1][0], srcA);
        u32 a1 = __shfl(pw[j][0][1], srcA),      b1 = __shfl(pw[j][1][1], srcA);
        u32 a2 = __shfl(pw[j][0][0], srcA + 16), b2 = __shfl(pw[j][1][0], srcA + 16);
        u32 a3 = __shfl(pw[j][0][1], srcA + 16), b3 = __shfl(pw[j][1][1], srcA + 16);
        u32x4 pbw = (u32x4){hi ? b0 : a0, hi ? b1 : a1, hi ? b2 : a2, hi ? b3 : a3};
        pb[j] = __builtin_bit_cast(bf16x8, pbw);
      }
#pragma unroll
      for (int dt = 0; dt < 4; dt++) {
        bf16x8 av = *(const bf16x8*)(Vt + (st * 4 + quad) * 512 + (dt * 16 + l15) * 8);
#pragma unroll
        for (int j = 0; j < 2; j++)
          oacc[j][dt] = __builtin_amdgcn_mfma_f32_16x16x32_bf16(av, pb[j], oacc[j][dt], 0, 0, 0);
      }
    }

    // ---- tail: kt = 12 (keys 192..195 valid; rest masked) ----
    {
      const int keyl = 192 + l15;
      const int keyc = (keyl > 195) ? 195 : keyl;
      bf16x8 bk0 = *(const bf16x8*)(kB + keyc * 64 + quad * 8);
      bf16x8 bk1 = *(const bf16x8*)(kB + keyc * 64 + 32 + quad * 8);
      const int key0 = 192 + quad * 4;
      const int hk0 = key0 / 14, wk0 = key0 - 14 * hk0;
      const bool valid = (quad == 0);
      u32 pwt[2][2];
#pragma unroll
      for (int j = 0; j < 2; j++) {
        f32x4 s = (f32x4){0.f, 0.f, 0.f, 0.f};
        s = __builtin_amdgcn_mfma_f32_16x16x32_bf16(bk0, aq0[j], s, 0, 0, 0);
        s = __builtin_amdgcn_mfma_f32_16x16x32_bf16(bk1, aq1[j], s, 0, 0, 0);
        float pr[4];
#pragma unroll
        for (int r = 0; r < 4; r++) {
          int cr = (wk0 + r >= 14) ? 1 : 0;
          int hk = hk0 + cr, wk = wk0 + r - 14 * cr;
          int ih = hbv[j] - hk; ih = ih < 0 ? 0 : ih;
          int iw = wqv[j] - wk + 13; iw = iw < 0 ? 0 : iw;
          float v = s[r] + TLh[wv][ih][l15 + 16 * j] + TLw[wv][iw][l15 + 16 * j];
          float pe = valid ? __expf(v) : 0.f;
          pr[r] = pe;
          sm[j] += pe;
        }
        pwt[j][0] = pack2bf(pr[0], pr[1]);
        pwt[j][1] = pack2bf(pr[2], pr[3]);
      }
      bf16x8 pb[2];
#pragma unroll
      for (int j = 0; j < 2; j++) {
        u32 a0 = __shfl(pwt[j][0], srcA);
        u32 a1 = __shfl(pwt[j][1], srcA);
        u32 a2 = __shfl(pwt[j][0], srcA + 16);
        u32 a3 = __shfl(pwt[j][1], srcA + 16);
        u32x4 pbw = (u32x4){hi ? 0u : a0, hi ? 0u : a1, hi ? 0u : a2, hi ? 0u : a3};
        pb[j] = __builtin_bit_cast(bf16x8, pbw);
      }
#pragma unroll
      for (int dt = 0; dt < 4; dt++) {
        bf16x8 av = (bf16x8){0, 0, 0, 0, 0, 0, 0, 0};
        if (quad < 2)
          av = *(const bf16x8*)(Vt + (24 + quad) * 512 + (dt * 16 + l15) * 8);
#pragma unroll
        for (int j = 0; j < 2; j++)
          oacc[j][dt] = __builtin_amdgcn_mfma_f32_16x16x32_bf16(av, pb[j], oacc[j][dt], 0, 0, 0);
      }
    }

    // ---- row sums, normalize, store per tile ----
#pragma unroll
    for (int j = 0; j < 2; j++) {
      float smj = sm[j];
      smj += __shfl_xor(smj, 16, 64);
      smj += __shfl_xor(smj, 32, 64);
      const float inv = 1.0f / smj;
      const int qrow = (qt0 + j) * 16 + l15;
      if (qrow < 196) {
        u16* op = aout + ((size_t)(b * 196 + qrow) * 12 + h) * 64;
#pragma unroll
        for (int dt = 0; dt < 4; dt++) {
          uint2 stv;
          stv.x = pack2bf(oacc[j][dt][0] * inv, oacc[j][dt][1] * inv);
          stv.y = pack2bf(oacc[j][dt][2] * inv, oacc[j][dt][3] * inv);
          *(uint2*)(op + dt * 16 + quad * 4) = stv;
        }
      }
    }
  }
}

// ---------------------------------------------------------------------------
extern "C" void kernel_launch(void* const* d_in, const int* in_sizes, int n_in,
                              void* d_out, int out_size, void* d_ws, size_t ws_size,
                              hipStream_t stream) {
  (void)in_sizes; (void)n_in; (void)out_size; (void)ws_size;
  const float* x      = (const float*)d_in[0];
  const float* qkv_w  = (const float*)d_in[1];
  const float* qkv_b  = (const float*)d_in[2];
  const float* rel_h  = (const float*)d_in[3];
  const float* rel_w  = (const float*)d_in[4];
  const float* proj_w = (const float*)d_in[5];
  const float* proj_b = (const float*)d_in[6];
  float* out = (float*)d_out;

  char* ws = (char*)d_ws;
  u16* xbf  = (u16*)(ws);              // aliased: x_bf16, then attn_out
  u16* qbuf = (u16*)(ws + 77070336);
  u16* kbuf = (u16*)(ws + 154140672);
  u16* vbuf = (u16*)(ws + 231211008);
  u16* wqb  = (u16*)(ws + 308281344);
  u16* wpb  = (u16*)(ws + 311820288);

  cvt_bf16<<<37632, 256, 0, stream>>>(x, xbf, 38535168 / 4);
  cvt_bf16<<<1728, 256, 0, stream>>>(qkv_w, wqb, 1769472 / 4);
  cvt_bf16<<<576, 256, 0, stream>>>(proj_w, wpb, 589824 / 4);

  // QKV: M=50176 (196 tiles), N=2304 (9 tiles), K=768
  gemm256<0, 9><<<1764, 512, 0, stream>>>(xbf, wqb, qkv_b, qbuf, kbuf, vbuf,
                                          nullptr);
  attn_fused<<<3072, 256, 0, stream>>>(qbuf, kbuf, vbuf, rel_h, rel_w, xbf);
  // proj: N=768 (3 tiles)
  gemm256<1, 3><<<588, 512, 0, stream>>>(xbf, wpb, proj_b, nullptr, nullptr,
                                         nullptr, out);
}